// Round 3
// baseline (354.244 us; speedup 1.0000x reference)
//
#include <hip/hip_runtime.h>
#include <cstddef>
#include <cstdint>

namespace {

constexpr int S = 48;
constexpr int N = S * S;        // 2304 positions
constexpr int D = 512;          // d_model
constexpr int DK = 64;          // head dim
constexpr int B = 2;
constexpr int BH = 16;          // b*heads
constexpr float SCALE = 0.125f;     // 1/sqrt(DK)
constexpr float INV2S2 = 0.02f;     // 1/(2*sigma^2), sigma=5

typedef __attribute__((ext_vector_type(8))) short short8;
typedef __attribute__((ext_vector_type(8))) unsigned short ushort8v;
typedef __attribute__((ext_vector_type(4))) float f32x4;

#define MFMA(a, b, c) __builtin_amdgcn_mfma_f32_16x16x32_bf16((a), (b), (c), 0, 0, 0)

// 3-way bf16 split: x ~= s1 + s2 + s3 (each RNE bf16), residual ~2^-26|x|
__device__ __forceinline__ void split3(float x, ushort& u1, ushort& u2, ushort& u3)
{
    uint b1 = __float_as_uint(x);
    uint r1 = (b1 + (0x7FFFu + ((b1 >> 16) & 1u))) & 0xFFFF0000u;
    u1 = (ushort)(r1 >> 16);
    float d1 = x - __uint_as_float(r1);                 // exact
    uint b2 = __float_as_uint(d1);
    uint r2 = (b2 + (0x7FFFu + ((b2 >> 16) & 1u))) & 0xFFFF0000u;
    u2 = (ushort)(r2 >> 16);
    float d2 = d1 - __uint_as_float(r2);                // exact
    uint b3 = __float_as_uint(d2);
    u3 = (ushort)((b3 + (0x7FFFu + ((b3 >> 16) & 1u))) >> 16);
}

// Copy a 64x64 ushort tile global -> LDS [64][72] (16B chunks, coalesced).
__device__ __forceinline__ void stage_tile(const ushort* __restrict__ g,
                                           ushort (*L)[72], int tid)
{
    #pragma unroll
    for (int it = 0; it < 2; it++) {
        int f = tid + 256 * it;
        int row = f >> 3, c8 = (f & 7) * 8;
        *(ushort8v*)&L[row][c8] = *(const ushort8v*)&g[(size_t)row * 64 + c8];
    }
}

__device__ __forceinline__ short8 frag(const ushort (*L)[72], int row, int k)
{
    return *(const short8*)&L[row][k];
}

// ---------------------------------------------------------------------------
// Kernel A: fused Q/K projection -> 3-way bf16 split arrays, per-head layout
// [bh][n][64].  out = X @ W^T + bias.  64x64 tile, 256 threads, 4x4/thread.
// ---------------------------------------------------------------------------
__global__ __launch_bounds__(256)
void proj_kernel(const float* __restrict__ qin, const float* __restrict__ kin,
                 const float* __restrict__ Wq, const float* __restrict__ bq,
                 const float* __restrict__ Wk, const float* __restrict__ bk,
                 ushort* __restrict__ q1, ushort* __restrict__ q2, ushort* __restrict__ q3,
                 ushort* __restrict__ k1, ushort* __restrict__ k2, ushort* __restrict__ k3)
{
    const float* X; const float* W; const float* bias;
    ushort *O1, *O2, *O3;
    if (blockIdx.z == 0) { X = qin; W = Wq; bias = bq; O1 = q1; O2 = q2; O3 = q3; }
    else                 { X = kin; W = Wk; bias = bk; O1 = k1; O2 = k2; O3 = k3; }

    __shared__ alignas(16) float As[16][68];
    __shared__ alignas(16) float Ws[16][68];

    const int tx = threadIdx.x, ty = threadIdx.y;
    const int tid = ty * 16 + tx;
    const int m0 = blockIdx.y * 64;           // position-row tile (0..71)
    const int hsel = blockIdx.x;              // head = n-tile (64 cols = 1 head)
    const int n0 = hsel * 64;
    const int lr = tid >> 2;
    const int lc = (tid & 3) << 2;

    float acc[4][4] = {};

    for (int k0 = 0; k0 < D; k0 += 16) {
        float4 av = *(const float4*)(X + (size_t)(m0 + lr) * D + k0 + lc);
        float4 wv = *(const float4*)(W + (size_t)(n0 + lr) * D + k0 + lc);
        As[lc+0][lr] = av.x; As[lc+1][lr] = av.y; As[lc+2][lr] = av.z; As[lc+3][lr] = av.w;
        Ws[lc+0][lr] = wv.x; Ws[lc+1][lr] = wv.y; Ws[lc+2][lr] = wv.z; Ws[lc+3][lr] = wv.w;
        __syncthreads();
        #pragma unroll
        for (int kk = 0; kk < 16; kk++) {
            float4 a  = *(const float4*)&As[kk][4*ty];
            float4 w4 = *(const float4*)&Ws[kk][4*tx];
            acc[0][0] += a.x*w4.x; acc[0][1] += a.x*w4.y; acc[0][2] += a.x*w4.z; acc[0][3] += a.x*w4.w;
            acc[1][0] += a.y*w4.x; acc[1][1] += a.y*w4.y; acc[1][2] += a.y*w4.z; acc[1][3] += a.y*w4.w;
            acc[2][0] += a.z*w4.x; acc[2][1] += a.z*w4.y; acc[2][2] += a.z*w4.z; acc[2][3] += a.z*w4.w;
            acc[3][0] += a.w*w4.x; acc[3][1] += a.w*w4.y; acc[3][2] += a.w*w4.z; acc[3][3] += a.w*w4.w;
        }
        __syncthreads();
    }
    float4 bv = *(const float4*)(bias + n0 + 4*tx);
    const int b = blockIdx.y / 36;
    #pragma unroll
    for (int i = 0; i < 4; i++) {
        int gm = m0 + 4*ty + i;
        int npos = gm - b * N;
        float4 o;
        o.x = acc[i][0] + bv.x; o.y = acc[i][1] + bv.y;
        o.z = acc[i][2] + bv.z; o.w = acc[i][3] + bv.w;
        ushort4 a1, a2, a3;
        split3(o.x, a1.x, a2.x, a3.x);
        split3(o.y, a1.y, a2.y, a3.y);
        split3(o.z, a1.z, a2.z, a3.z);
        split3(o.w, a1.w, a2.w, a3.w);
        size_t dst = ((size_t)(b * 8 + hsel) * N + npos) * 64 + 4 * tx;
        *(ushort4*)&O1[dst] = a1;
        *(ushort4*)&O2[dst] = a2;
        *(ushort4*)&O3[dst] = a3;
    }
}

// ---------------------------------------------------------------------------
// Kernel B: per-key argmax over queries of raw scores.  3-split, 6 MFMA
// products -> dot error ~ fp32 noise level.  Block: 64 keys; loops q-tiles.
// K fragments are extracted to registers once; the SAME LDS buffer is then
// reused for streaming Q tiles (28.7 KB total -> 5 blocks/CU).
// ---------------------------------------------------------------------------
__global__ __launch_bounds__(256)
void argmax_kernel(const ushort* __restrict__ Q1, const ushort* __restrict__ Q2,
                   const ushort* __restrict__ Q3, const ushort* __restrict__ K1,
                   const ushort* __restrict__ K2, const ushort* __restrict__ K3,
                   int* __restrict__ idxout)
{
    const int bh = blockIdx.y;
    const int kt0 = blockIdx.x * 64;
    const size_t hb = (size_t)bh * N;

    __shared__ alignas(16) ushort buf[3][64][72];   // K staging, then Q stream
    __shared__ float redv[2][64];
    __shared__ int   redq[2][64];

    const int tid = threadIdx.x;
    const int lane = tid & 63, w = tid >> 6;
    const int wk = w >> 1, wq = w & 1;
    const int lg = lane >> 4, ln = lane & 15;

    stage_tile(K1 + (hb + kt0) * 64, buf[0], tid);
    stage_tile(K2 + (hb + kt0) * 64, buf[1], tid);
    stage_tile(K3 + (hb + kt0) * 64, buf[2], tid);
    __syncthreads();

    short8 A[3][2][2];                   // [comp][mt][chunk]
    #pragma unroll
    for (int mt = 0; mt < 2; mt++)
        #pragma unroll
        for (int c = 0; c < 2; c++) {
            int row = 32 * wk + 16 * mt + ln, k = 32 * c + 8 * lg;
            A[0][mt][c] = frag(buf[0], row, k);
            A[1][mt][c] = frag(buf[1], row, k);
            A[2][mt][c] = frag(buf[2], row, k);
        }
    __syncthreads();                      // K fully consumed; buf now free

    float bestv[2][4];
    int   bestq[2][4];
    #pragma unroll
    for (int mt = 0; mt < 2; mt++)
        #pragma unroll
        for (int r = 0; r < 4; r++) { bestv[mt][r] = -3e38f; bestq[mt][r] = 0; }

    for (int qt = 0; qt < N; qt += 64) {
        stage_tile(Q1 + (hb + qt) * 64, buf[0], tid);
        stage_tile(Q2 + (hb + qt) * 64, buf[1], tid);
        stage_tile(Q3 + (hb + qt) * 64, buf[2], tid);
        __syncthreads();
        #pragma unroll
        for (int nt = 0; nt < 2; nt++) {
            short8 Bv0[2], Bv1[2], Bv2[2];
            #pragma unroll
            for (int c = 0; c < 2; c++) {
                int row = 32 * wq + 16 * nt + ln, k = 32 * c + 8 * lg;
                Bv0[c] = frag(buf[0], row, k);
                Bv1[c] = frag(buf[1], row, k);
                Bv2[c] = frag(buf[2], row, k);
            }
            #pragma unroll
            for (int mt = 0; mt < 2; mt++) {
                f32x4 acc = {0.f, 0.f, 0.f, 0.f};
                acc = MFMA(A[0][mt][0], Bv0[0], acc);
                acc = MFMA(A[0][mt][1], Bv0[1], acc);
                acc = MFMA(A[0][mt][0], Bv1[0], acc);
                acc = MFMA(A[0][mt][1], Bv1[1], acc);
                acc = MFMA(A[1][mt][0], Bv0[0], acc);
                acc = MFMA(A[1][mt][1], Bv0[1], acc);
                acc = MFMA(A[0][mt][0], Bv2[0], acc);
                acc = MFMA(A[0][mt][1], Bv2[1], acc);
                acc = MFMA(A[1][mt][0], Bv1[0], acc);
                acc = MFMA(A[1][mt][1], Bv1[1], acc);
                acc = MFMA(A[2][mt][0], Bv0[0], acc);
                acc = MFMA(A[2][mt][1], Bv0[1], acc);
                int q = qt + 32 * wq + 16 * nt + ln;
                #pragma unroll
                for (int r = 0; r < 4; r++)
                    if (acc[r] > bestv[mt][r]) { bestv[mt][r] = acc[r]; bestq[mt][r] = q; }
            }
        }
        __syncthreads();
    }
    #pragma unroll
    for (int d = 1; d < 16; d <<= 1) {
        #pragma unroll
        for (int mt = 0; mt < 2; mt++)
            #pragma unroll
            for (int r = 0; r < 4; r++) {
                float ov = __shfl_xor(bestv[mt][r], d);
                int   oq = __shfl_xor(bestq[mt][r], d);
                if (ov > bestv[mt][r] || (ov == bestv[mt][r] && oq < bestq[mt][r])) {
                    bestv[mt][r] = ov; bestq[mt][r] = oq;
                }
            }
    }
    if (ln == 0) {
        #pragma unroll
        for (int mt = 0; mt < 2; mt++)
            #pragma unroll
            for (int r = 0; r < 4; r++) {
                int key = 32 * wk + 16 * mt + 4 * lg + r;
                redv[wq][key] = bestv[mt][r];
                redq[wq][key] = bestq[mt][r];
            }
    }
    __syncthreads();
    if (tid < 64) {
        float va = redv[0][tid], vb = redv[1][tid];
        int   qa = redq[0][tid], qb = redq[1][tid];
        int bi = (vb > va || (vb == va && qb < qa)) ? qb : qa;
        idxout[hb + kt0 + tid] = bi;
    }
}

// ---------------------------------------------------------------------------
// Kernel C: row pass (softmax over k, NO max subtraction -- scores bounded):
// denom and x0.  Block: 64 queries (frags resident); streams k-tiles through
// the reused staging buffer.  2-split, 3 MFMA products.
// ---------------------------------------------------------------------------
__global__ __launch_bounds__(256)
void rowpass_kernel(const ushort* __restrict__ Q1, const ushort* __restrict__ Q2,
                    const ushort* __restrict__ K1, const ushort* __restrict__ K2,
                    const int* __restrict__ idxbuf, const float* __restrict__ value0,
                    float* __restrict__ denomo, float* __restrict__ x0o)
{
    const int bh = blockIdx.y, b = bh >> 3;
    const int q0 = blockIdx.x * 64;
    const size_t hb = (size_t)bh * N;

    __shared__ alignas(16) ushort buf[2][64][72];   // Q staging, then K stream
    __shared__ float F[48][48];
    __shared__ int ixi[64], iyi[64];
    __shared__ float v0s[64];
    __shared__ float red[2][64][2];

    const int tid = threadIdx.x;
    const int lane = tid & 63, w = tid >> 6;
    const int wk = w >> 1, wq = w & 1;
    const int lg = lane >> 4, ln = lane & 15;

    for (int i = tid; i < 48 * 48; i += 256) {
        int a = i / 48, j = i % 48;
        float lj = -1.0f + (2.0f / 47.0f) * (float)j;
        float dd = lj - (float)a;
        F[a][j] = __expf(-dd * dd * INV2S2);
    }
    stage_tile(Q1 + (hb + q0) * 64, buf[0], tid);
    stage_tile(Q2 + (hb + q0) * 64, buf[1], tid);
    __syncthreads();

    short8 Bq[2][2][2];                  // [comp][nt][chunk]
    int qx_[2], qy_[2];
    #pragma unroll
    for (int nt = 0; nt < 2; nt++) {
        #pragma unroll
        for (int c = 0; c < 2; c++) {
            int row = 32 * wq + 16 * nt + ln, k = 32 * c + 8 * lg;
            Bq[0][nt][c] = frag(buf[0], row, k);
            Bq[1][nt][c] = frag(buf[1], row, k);
        }
        int qq = q0 + 32 * wq + 16 * nt + ln;
        qx_[nt] = qq % 48; qy_[nt] = qq / 48;
    }
    __syncthreads();                      // Q consumed; buf free for K

    float l[2] = {0.f, 0.f}, a0[2] = {0.f, 0.f};

    for (int kt = 0; kt < N; kt += 64) {
        stage_tile(K1 + (hb + kt) * 64, buf[0], tid);
        stage_tile(K2 + (hb + kt) * 64, buf[1], tid);
        if (tid < 64) {
            int v = idxbuf[hb + kt + tid];
            ixi[tid] = v % 48; iyi[tid] = v / 48;
            v0s[tid] = value0[(size_t)b * N + kt + tid];
        }
        __syncthreads();
        short8 A[2][2][2];               // [comp][mt][chunk]
        #pragma unroll
        for (int mt = 0; mt < 2; mt++)
            #pragma unroll
            for (int c = 0; c < 2; c++) {
                int row = 32 * wk + 16 * mt + ln, k = 32 * c + 8 * lg;
                A[0][mt][c] = frag(buf[0], row, k);
                A[1][mt][c] = frag(buf[1], row, k);
            }
        #pragma unroll
        for (int nt = 0; nt < 2; nt++) {
            #pragma unroll
            for (int mt = 0; mt < 2; mt++) {
                f32x4 acc = {0.f, 0.f, 0.f, 0.f};
                acc = MFMA(A[0][mt][0], Bq[0][nt][0], acc);
                acc = MFMA(A[0][mt][1], Bq[0][nt][1], acc);
                acc = MFMA(A[0][mt][0], Bq[1][nt][0], acc);
                acc = MFMA(A[0][mt][1], Bq[1][nt][1], acc);
                acc = MFMA(A[1][mt][0], Bq[0][nt][0], acc);
                acc = MFMA(A[1][mt][1], Bq[0][nt][1], acc);
                #pragma unroll
                for (int r = 0; r < 4; r++) {
                    int kl = 32 * wk + 16 * mt + 4 * lg + r;
                    float s = acc[r] * F[ixi[kl]][qx_[nt]] * F[iyi[kl]][qy_[nt]] * SCALE;
                    float e = __expf(s);
                    l[nt]  += e;
                    a0[nt] += e * v0s[kl];
                }
            }
        }
        __syncthreads();
    }
    // sum across lane-groups (keys) within the wave
    #pragma unroll
    for (int d = 16; d < 64; d <<= 1) {
        #pragma unroll
        for (int nt = 0; nt < 2; nt++) {
            l[nt]  += __shfl_xor(l[nt], d);
            a0[nt] += __shfl_xor(a0[nt], d);
        }
    }
    if (lane < 16) {
        #pragma unroll
        for (int nt = 0; nt < 2; nt++) {
            int ql = 32 * wq + 16 * nt + ln;
            red[wk][ql][0] = l[nt];
            red[wk][ql][1] = a0[nt];
        }
    }
    __syncthreads();
    if (tid < 64) {
        float L = red[0][tid][0] + red[1][tid][0];
        float A = red[0][tid][1] + red[1][tid][1];
        denomo[hb + q0 + tid] = L;
        x0o[hb + q0 + tid] = A / L;
    }
}

// ---------------------------------------------------------------------------
// Kernel D: column pass.  x1[k] = sum_q exp(s) * v1[q]/denom[q].
// Block: 64 keys (frags resident); streams q-tiles through reused buffer.
// ---------------------------------------------------------------------------
__global__ __launch_bounds__(256)
void colpass_kernel(const ushort* __restrict__ Q1, const ushort* __restrict__ Q2,
                    const ushort* __restrict__ K1, const ushort* __restrict__ K2,
                    const int* __restrict__ idxbuf, const float* __restrict__ value1,
                    const float* __restrict__ denomo, float* __restrict__ x1o)
{
    const int bh = blockIdx.y, b = bh >> 3;
    const int kt0 = blockIdx.x * 64;
    const size_t hb = (size_t)bh * N;

    __shared__ alignas(16) ushort buf[2][64][72];   // K staging, then Q stream
    __shared__ float F[48][48];
    __shared__ int ixi[64], iyi[64];
    __shared__ float wvs[64];
    __shared__ int qxs[64], qys[64];
    __shared__ float redx[2][64];

    const int tid = threadIdx.x;
    const int lane = tid & 63, w = tid >> 6;
    const int wk = w >> 1, wq = w & 1;
    const int lg = lane >> 4, ln = lane & 15;

    for (int i = tid; i < 48 * 48; i += 256) {
        int a = i / 48, j = i % 48;
        float lj = -1.0f + (2.0f / 47.0f) * (float)j;
        float dd = lj - (float)a;
        F[a][j] = __expf(-dd * dd * INV2S2);
    }
    stage_tile(K1 + (hb + kt0) * 64, buf[0], tid);
    stage_tile(K2 + (hb + kt0) * 64, buf[1], tid);
    if (tid < 64) {
        int v = idxbuf[hb + kt0 + tid];
        ixi[tid] = v % 48; iyi[tid] = v / 48;
    }
    __syncthreads();

    short8 A[2][2][2];
    #pragma unroll
    for (int mt = 0; mt < 2; mt++)
        #pragma unroll
        for (int c = 0; c < 2; c++) {
            int row = 32 * wk + 16 * mt + ln, k = 32 * c + 8 * lg;
            A[0][mt][c] = frag(buf[0], row, k);
            A[1][mt][c] = frag(buf[1], row, k);
        }
    int ixr[2][4], iyr[2][4];
    #pragma unroll
    for (int mt = 0; mt < 2; mt++)
        #pragma unroll
        for (int r = 0; r < 4; r++) {
            int kl = 32 * wk + 16 * mt + 4 * lg + r;
            ixr[mt][r] = ixi[kl]; iyr[mt][r] = iyi[kl];
        }
    __syncthreads();                      // K consumed; buf free for Q

    float acc1[2][4] = {};

    for (int qt = 0; qt < N; qt += 64) {
        stage_tile(Q1 + (hb + qt) * 64, buf[0], tid);
        stage_tile(Q2 + (hb + qt) * 64, buf[1], tid);
        if (tid < 64) {
            int qg = qt + tid;
            wvs[tid] = value1[(size_t)b * N + qg] / denomo[hb + qg];
            qxs[tid] = qg % 48; qys[tid] = qg / 48;
        }
        __syncthreads();
        #pragma unroll
        for (int nt = 0; nt < 2; nt++) {
            short8 Bv0[2], Bv1[2];
            #pragma unroll
            for (int c = 0; c < 2; c++) {
                int row = 32 * wq + 16 * nt + ln, k = 32 * c + 8 * lg;
                Bv0[c] = frag(buf[0], row, k);
                Bv1[c] = frag(buf[1], row, k);
            }
            int qi = 32 * wq + 16 * nt + ln;
            int qx = qxs[qi], qy = qys[qi];
            float wq_ = wvs[qi];
            #pragma unroll
            for (int mt = 0; mt < 2; mt++) {
                f32x4 acc = {0.f, 0.f, 0.f, 0.f};
                acc = MFMA(A[0][mt][0], Bv0[0], acc);
                acc = MFMA(A[0][mt][1], Bv0[1], acc);
                acc = MFMA(A[0][mt][0], Bv1[0], acc);
                acc = MFMA(A[0][mt][1], Bv1[1], acc);
                acc = MFMA(A[1][mt][0], Bv0[0], acc);
                acc = MFMA(A[1][mt][1], Bv0[1], acc);
                #pragma unroll
                for (int r = 0; r < 4; r++) {
                    float s = acc[r] * F[ixr[mt][r]][qx] * F[iyr[mt][r]][qy] * SCALE;
                    acc1[mt][r] += __expf(s) * wq_;
                }
            }
        }
        __syncthreads();
    }
    #pragma unroll
    for (int d = 1; d < 16; d <<= 1)
        #pragma unroll
        for (int mt = 0; mt < 2; mt++)
            #pragma unroll
            for (int r = 0; r < 4; r++)
                acc1[mt][r] += __shfl_xor(acc1[mt][r], d);
    if (ln == 0) {
        #pragma unroll
        for (int mt = 0; mt < 2; mt++)
            #pragma unroll
            for (int r = 0; r < 4; r++)
                redx[wq][32 * wk + 16 * mt + 4 * lg + r] = acc1[mt][r];
    }
    __syncthreads();
    if (tid < 64)
        x1o[hb + kt0 + tid] = redx[0][tid] + redx[1][tid];
}

// ---------------------------------------------------------------------------
// Kernel E: out[b,q,k] = (1/8) * sum_h x0[b,h,q] * x1[b,h,k]   (float4 stores)
// ---------------------------------------------------------------------------
__global__ __launch_bounds__(256)
void outer_kernel(const float* __restrict__ x0, const float* __restrict__ x1,
                  float* __restrict__ out)
{
    const int b = blockIdx.z;
    const int q0 = blockIdx.y * 32, k0 = blockIdx.x * 32;
    __shared__ float x0s[8][32];
    __shared__ float x1s[8][32];
    const int tid = threadIdx.x;
    {
        int hh = tid >> 5, i = tid & 31;
        x0s[hh][i] = x0[(size_t)(b * 8 + hh) * N + q0 + i];
        x1s[hh][i] = x1[(size_t)(b * 8 + hh) * N + k0 + i];
    }
    __syncthreads();
    const int row = tid >> 3, c4 = (tid & 7) * 4;
    float4 a = {0.f, 0.f, 0.f, 0.f};
    #pragma unroll
    for (int hh = 0; hh < 8; hh++) {
        float s = x0s[hh][row];
        a.x += s * x1s[hh][c4 + 0];
        a.y += s * x1s[hh][c4 + 1];
        a.z += s * x1s[hh][c4 + 2];
        a.w += s * x1s[hh][c4 + 3];
    }
    a.x *= 0.125f; a.y *= 0.125f; a.z *= 0.125f; a.w *= 0.125f;
    *(float4*)(out + (size_t)b * N * N + (size_t)(q0 + row) * N + k0 + c4) = a;
}

} // namespace

extern "C" void kernel_launch(void* const* d_in, const int* in_sizes, int n_in,
                              void* d_out, int out_size, void* d_ws, size_t ws_size,
                              hipStream_t stream) {
    const float* qin = (const float*)d_in[0];
    const float* kin = (const float*)d_in[1];
    const float* v0  = (const float*)d_in[2];
    const float* v1  = (const float*)d_in[3];
    const float* Wq  = (const float*)d_in[4];
    const float* bq  = (const float*)d_in[5];
    const float* Wk  = (const float*)d_in[6];
    const float* bk  = (const float*)d_in[7];
    float* out = (float*)d_out;

    // 3-way bf16-split Q/K live in d_out scratch (6 arrays x 4.72 MB = 28.3 MB
    // of the 42.5 MB output buffer); outer_kernel fully overwrites d_out last.
    const size_t ARR = (size_t)BH * N * DK;   // 2359296 elements per split array
    ushort* Q1 = (ushort*)d_out;
    ushort* Q2 = Q1 + ARR;
    ushort* Q3 = Q2 + ARR;
    ushort* K1 = Q3 + ARR;
    ushort* K2 = K1 + ARR;
    ushort* K3 = K2 + ARR;

    int*   idxb = (int*)d_ws;
    float* den  = (float*)(idxb + (size_t)BH * N);
    float* x0b  = den + (size_t)BH * N;
    float* x1b  = x0b + (size_t)BH * N;

    proj_kernel   <<<dim3(8, 72, 2),  dim3(16, 16), 0, stream>>>(qin, kin, Wq, bq, Wk, bk,
                                                                 Q1, Q2, Q3, K1, K2, K3);
    argmax_kernel <<<dim3(36, 16),    dim3(256),    0, stream>>>(Q1, Q2, Q3, K1, K2, K3, idxb);
    rowpass_kernel<<<dim3(36, 16),    dim3(256),    0, stream>>>(Q1, Q2, K1, K2, idxb, v0,
                                                                 den, x0b);
    colpass_kernel<<<dim3(36, 16),    dim3(256),    0, stream>>>(Q1, Q2, K1, K2, idxb, v1,
                                                                 den, x1b);
    outer_kernel  <<<dim3(72, 72, 2), dim3(256),    0, stream>>>(x0b, x1b, out);
}

// Round 4
// 311.280 us; speedup vs baseline: 1.1380x; 1.1380x over previous
//
#include <hip/hip_runtime.h>
#include <cstddef>
#include <cstdint>

namespace {

constexpr int S = 48;
constexpr int N = S * S;        // 2304 positions
constexpr int D = 512;          // d_model
constexpr int DK = 64;          // head dim
constexpr int B = 2;
constexpr int BH = 16;          // b*heads
constexpr int BHN = BH * N;     // 36864
constexpr int G = 4;            // reduction-dim split factor
constexpr int CHUNK = N / G;    // 576 positions = 9 tiles of 64
constexpr float SCALE = 0.125f;     // 1/sqrt(DK)
constexpr float INV2S2 = 0.02f;     // 1/(2*sigma^2), sigma=5

typedef __attribute__((ext_vector_type(8))) short short8;
typedef __attribute__((ext_vector_type(8))) unsigned short ushort8v;
typedef __attribute__((ext_vector_type(4))) float f32x4;

#define MFMA(a, b, c) __builtin_amdgcn_mfma_f32_16x16x32_bf16((a), (b), (c), 0, 0, 0)

// 3-way bf16 split: x ~= s1 + s2 + s3 (each RNE bf16), residual ~2^-26|x|
__device__ __forceinline__ void split3(float x, ushort& u1, ushort& u2, ushort& u3)
{
    uint b1 = __float_as_uint(x);
    uint r1 = (b1 + (0x7FFFu + ((b1 >> 16) & 1u))) & 0xFFFF0000u;
    u1 = (ushort)(r1 >> 16);
    float d1 = x - __uint_as_float(r1);                 // exact
    uint b2 = __float_as_uint(d1);
    uint r2 = (b2 + (0x7FFFu + ((b2 >> 16) & 1u))) & 0xFFFF0000u;
    u2 = (ushort)(r2 >> 16);
    float d2 = d1 - __uint_as_float(r2);                // exact
    uint b3 = __float_as_uint(d2);
    u3 = (ushort)((b3 + (0x7FFFu + ((b3 >> 16) & 1u))) >> 16);
}

// Copy a 64x64 ushort tile global -> LDS [64][72] (16B chunks, coalesced).
__device__ __forceinline__ void stage_tile(const ushort* __restrict__ g,
                                           ushort (*L)[72], int tid)
{
    #pragma unroll
    for (int it = 0; it < 2; it++) {
        int f = tid + 256 * it;
        int row = f >> 3, c8 = (f & 7) * 8;
        *(ushort8v*)&L[row][c8] = *(const ushort8v*)&g[(size_t)row * 64 + c8];
    }
}

__device__ __forceinline__ short8 frag(const ushort (*L)[72], int row, int k)
{
    return *(const short8*)&L[row][k];
}

// ---------------------------------------------------------------------------
// Kernel A: fused Q/K projection -> 3-way bf16 split arrays, per-head layout
// [bh][n][64].  out = X @ W^T + bias.  64x64 tile, 256 threads, 4x4/thread.
// ---------------------------------------------------------------------------
__global__ __launch_bounds__(256)
void proj_kernel(const float* __restrict__ qin, const float* __restrict__ kin,
                 const float* __restrict__ Wq, const float* __restrict__ bq,
                 const float* __restrict__ Wk, const float* __restrict__ bk,
                 ushort* __restrict__ q1, ushort* __restrict__ q2, ushort* __restrict__ q3,
                 ushort* __restrict__ k1, ushort* __restrict__ k2, ushort* __restrict__ k3)
{
    const float* X; const float* W; const float* bias;
    ushort *O1, *O2, *O3;
    if (blockIdx.z == 0) { X = qin; W = Wq; bias = bq; O1 = q1; O2 = q2; O3 = q3; }
    else                 { X = kin; W = Wk; bias = bk; O1 = k1; O2 = k2; O3 = k3; }

    __shared__ alignas(16) float As[16][68];
    __shared__ alignas(16) float Ws[16][68];

    const int tx = threadIdx.x, ty = threadIdx.y;
    const int tid = ty * 16 + tx;
    const int m0 = blockIdx.y * 64;           // position-row tile (0..71)
    const int hsel = blockIdx.x;              // head = n-tile (64 cols = 1 head)
    const int n0 = hsel * 64;
    const int lr = tid >> 2;
    const int lc = (tid & 3) << 2;

    float acc[4][4] = {};

    for (int k0 = 0; k0 < D; k0 += 16) {
        float4 av = *(const float4*)(X + (size_t)(m0 + lr) * D + k0 + lc);
        float4 wv = *(const float4*)(W + (size_t)(n0 + lr) * D + k0 + lc);
        As[lc+0][lr] = av.x; As[lc+1][lr] = av.y; As[lc+2][lr] = av.z; As[lc+3][lr] = av.w;
        Ws[lc+0][lr] = wv.x; Ws[lc+1][lr] = wv.y; Ws[lc+2][lr] = wv.z; Ws[lc+3][lr] = wv.w;
        __syncthreads();
        #pragma unroll
        for (int kk = 0; kk < 16; kk++) {
            float4 a  = *(const float4*)&As[kk][4*ty];
            float4 w4 = *(const float4*)&Ws[kk][4*tx];
            acc[0][0] += a.x*w4.x; acc[0][1] += a.x*w4.y; acc[0][2] += a.x*w4.z; acc[0][3] += a.x*w4.w;
            acc[1][0] += a.y*w4.x; acc[1][1] += a.y*w4.y; acc[1][2] += a.y*w4.z; acc[1][3] += a.y*w4.w;
            acc[2][0] += a.z*w4.x; acc[2][1] += a.z*w4.y; acc[2][2] += a.z*w4.z; acc[2][3] += a.z*w4.w;
            acc[3][0] += a.w*w4.x; acc[3][1] += a.w*w4.y; acc[3][2] += a.w*w4.z; acc[3][3] += a.w*w4.w;
        }
        __syncthreads();
    }
    float4 bv = *(const float4*)(bias + n0 + 4*tx);
    const int b = blockIdx.y / 36;
    #pragma unroll
    for (int i = 0; i < 4; i++) {
        int gm = m0 + 4*ty + i;
        int npos = gm - b * N;
        float4 o;
        o.x = acc[i][0] + bv.x; o.y = acc[i][1] + bv.y;
        o.z = acc[i][2] + bv.z; o.w = acc[i][3] + bv.w;
        ushort4 a1, a2, a3;
        split3(o.x, a1.x, a2.x, a3.x);
        split3(o.y, a1.y, a2.y, a3.y);
        split3(o.z, a1.z, a2.z, a3.z);
        split3(o.w, a1.w, a2.w, a3.w);
        size_t dst = ((size_t)(b * 8 + hsel) * N + npos) * 64 + 4 * tx;
        *(ushort4*)&O1[dst] = a1;
        *(ushort4*)&O2[dst] = a2;
        *(ushort4*)&O3[dst] = a3;
    }
}

// ---------------------------------------------------------------------------
// Kernel B: per-key argmax over a 576-query CHUNK of raw scores.  3-split,
// 6 MFMA products.  grid (36 ktiles, 16 bh, G chunks); partial best written
// to argV/argQ[g].  Tie-break: lowest q (ascending scan + strict >).
// ---------------------------------------------------------------------------
__global__ __launch_bounds__(256)
void argmax_kernel(const ushort* __restrict__ Q1, const ushort* __restrict__ Q2,
                   const ushort* __restrict__ Q3, const ushort* __restrict__ K1,
                   const ushort* __restrict__ K2, const ushort* __restrict__ K3,
                   float* __restrict__ argV, int* __restrict__ argQ)
{
    const int bh = blockIdx.y;
    const int kt0 = blockIdx.x * 64;
    const int g = blockIdx.z;
    const size_t hb = (size_t)bh * N;

    __shared__ alignas(16) ushort buf[3][64][72];   // K staging, then Q stream
    __shared__ float redv[2][64];
    __shared__ int   redq[2][64];

    const int tid = threadIdx.x;
    const int lane = tid & 63, w = tid >> 6;
    const int wk = w >> 1, wq = w & 1;
    const int lg = lane >> 4, ln = lane & 15;

    stage_tile(K1 + (hb + kt0) * 64, buf[0], tid);
    stage_tile(K2 + (hb + kt0) * 64, buf[1], tid);
    stage_tile(K3 + (hb + kt0) * 64, buf[2], tid);
    __syncthreads();

    short8 A[3][2][2];                   // [comp][mt][chunk]
    #pragma unroll
    for (int mt = 0; mt < 2; mt++)
        #pragma unroll
        for (int c = 0; c < 2; c++) {
            int row = 32 * wk + 16 * mt + ln, k = 32 * c + 8 * lg;
            A[0][mt][c] = frag(buf[0], row, k);
            A[1][mt][c] = frag(buf[1], row, k);
            A[2][mt][c] = frag(buf[2], row, k);
        }
    __syncthreads();                      // K fully consumed; buf now free

    float bestv[2][4];
    int   bestq[2][4];
    #pragma unroll
    for (int mt = 0; mt < 2; mt++)
        #pragma unroll
        for (int r = 0; r < 4; r++) { bestv[mt][r] = -3e38f; bestq[mt][r] = 0; }

    for (int qt = g * CHUNK; qt < (g + 1) * CHUNK; qt += 64) {
        stage_tile(Q1 + (hb + qt) * 64, buf[0], tid);
        stage_tile(Q2 + (hb + qt) * 64, buf[1], tid);
        stage_tile(Q3 + (hb + qt) * 64, buf[2], tid);
        __syncthreads();
        #pragma unroll
        for (int nt = 0; nt < 2; nt++) {
            short8 Bv0[2], Bv1[2], Bv2[2];
            #pragma unroll
            for (int c = 0; c < 2; c++) {
                int row = 32 * wq + 16 * nt + ln, k = 32 * c + 8 * lg;
                Bv0[c] = frag(buf[0], row, k);
                Bv1[c] = frag(buf[1], row, k);
                Bv2[c] = frag(buf[2], row, k);
            }
            #pragma unroll
            for (int mt = 0; mt < 2; mt++) {
                f32x4 acc = {0.f, 0.f, 0.f, 0.f};
                acc = MFMA(A[0][mt][0], Bv0[0], acc);
                acc = MFMA(A[0][mt][1], Bv0[1], acc);
                acc = MFMA(A[0][mt][0], Bv1[0], acc);
                acc = MFMA(A[0][mt][1], Bv1[1], acc);
                acc = MFMA(A[1][mt][0], Bv0[0], acc);
                acc = MFMA(A[1][mt][1], Bv0[1], acc);
                acc = MFMA(A[0][mt][0], Bv2[0], acc);
                acc = MFMA(A[0][mt][1], Bv2[1], acc);
                acc = MFMA(A[1][mt][0], Bv1[0], acc);
                acc = MFMA(A[1][mt][1], Bv1[1], acc);
                acc = MFMA(A[2][mt][0], Bv0[0], acc);
                acc = MFMA(A[2][mt][1], Bv0[1], acc);
                int q = qt + 32 * wq + 16 * nt + ln;
                #pragma unroll
                for (int r = 0; r < 4; r++)
                    if (acc[r] > bestv[mt][r]) { bestv[mt][r] = acc[r]; bestq[mt][r] = q; }
            }
        }
        __syncthreads();
    }
    #pragma unroll
    for (int d = 1; d < 16; d <<= 1) {
        #pragma unroll
        for (int mt = 0; mt < 2; mt++)
            #pragma unroll
            for (int r = 0; r < 4; r++) {
                float ov = __shfl_xor(bestv[mt][r], d);
                int   oq = __shfl_xor(bestq[mt][r], d);
                if (ov > bestv[mt][r] || (ov == bestv[mt][r] && oq < bestq[mt][r])) {
                    bestv[mt][r] = ov; bestq[mt][r] = oq;
                }
            }
    }
    if (ln == 0) {
        #pragma unroll
        for (int mt = 0; mt < 2; mt++)
            #pragma unroll
            for (int r = 0; r < 4; r++) {
                int key = 32 * wk + 16 * mt + 4 * lg + r;
                redv[wq][key] = bestv[mt][r];
                redq[wq][key] = bestq[mt][r];
            }
    }
    __syncthreads();
    if (tid < 64) {
        float va = redv[0][tid], vb = redv[1][tid];
        int   qa = redq[0][tid], qb = redq[1][tid];
        int   bi = (vb > va || (vb == va && qb < qa)) ? qb : qa;
        float bv = fmaxf(va, vb);
        size_t o = (size_t)g * BHN + hb + kt0 + tid;
        argV[o] = bv;
        argQ[o] = bi;
    }
}

// Combine G partial argmaxes (ascending g keeps lowest q on ties).
__global__ __launch_bounds__(256)
void argcombine_kernel(const float* __restrict__ argV, const int* __restrict__ argQ,
                       int* __restrict__ idxout)
{
    int i = blockIdx.x * 256 + threadIdx.x;
    if (i >= BHN) return;
    float bv = argV[i]; int bq = argQ[i];
    #pragma unroll
    for (int g = 1; g < G; g++) {
        float v = argV[(size_t)g * BHN + i];
        int   q = argQ[(size_t)g * BHN + i];
        if (v > bv) { bv = v; bq = q; }
    }
    idxout[i] = bq;
}

// ---------------------------------------------------------------------------
// Kernel C: row pass over a 576-key chunk (softmax over k, no max subtract --
// scores bounded).  Partial l, a0 written per chunk.  grid (36 qtiles,16,G).
// ---------------------------------------------------------------------------
__global__ __launch_bounds__(256)
void rowpass_kernel(const ushort* __restrict__ Q1, const ushort* __restrict__ Q2,
                    const ushort* __restrict__ K1, const ushort* __restrict__ K2,
                    const int* __restrict__ idxbuf, const float* __restrict__ value0,
                    float* __restrict__ rowPl, float* __restrict__ rowPa)
{
    const int bh = blockIdx.y, b = bh >> 3;
    const int q0 = blockIdx.x * 64;
    const int g = blockIdx.z;
    const size_t hb = (size_t)bh * N;

    __shared__ alignas(16) ushort buf[2][64][72];   // Q staging, then K stream
    __shared__ float F[48][49];
    __shared__ int ixi[64], iyi[64];
    __shared__ float v0s[64];
    __shared__ float red[2][64][2];

    const int tid = threadIdx.x;
    const int lane = tid & 63, w = tid >> 6;
    const int wk = w >> 1, wq = w & 1;
    const int lg = lane >> 4, ln = lane & 15;

    for (int i = tid; i < 48 * 48; i += 256) {
        int a = i / 48, j = i % 48;
        float lj = -1.0f + (2.0f / 47.0f) * (float)j;
        float dd = lj - (float)a;
        F[a][j] = __expf(-dd * dd * INV2S2);
    }
    stage_tile(Q1 + (hb + q0) * 64, buf[0], tid);
    stage_tile(Q2 + (hb + q0) * 64, buf[1], tid);
    __syncthreads();

    short8 Bq[2][2][2];                  // [comp][nt][chunk]
    int qx_[2], qy_[2];
    #pragma unroll
    for (int nt = 0; nt < 2; nt++) {
        #pragma unroll
        for (int c = 0; c < 2; c++) {
            int row = 32 * wq + 16 * nt + ln, k = 32 * c + 8 * lg;
            Bq[0][nt][c] = frag(buf[0], row, k);
            Bq[1][nt][c] = frag(buf[1], row, k);
        }
        int qq = q0 + 32 * wq + 16 * nt + ln;
        qx_[nt] = qq % 48; qy_[nt] = qq / 48;
    }
    __syncthreads();                      // Q consumed; buf free for K

    float l[2] = {0.f, 0.f}, a0[2] = {0.f, 0.f};

    for (int kt = g * CHUNK; kt < (g + 1) * CHUNK; kt += 64) {
        stage_tile(K1 + (hb + kt) * 64, buf[0], tid);
        stage_tile(K2 + (hb + kt) * 64, buf[1], tid);
        if (tid < 64) {
            int v = idxbuf[hb + kt + tid];
            ixi[tid] = v % 48; iyi[tid] = v / 48;
            v0s[tid] = value0[(size_t)b * N + kt + tid];
        }
        __syncthreads();
        short8 A[2][2][2];               // [comp][mt][chunk]
        #pragma unroll
        for (int mt = 0; mt < 2; mt++)
            #pragma unroll
            for (int c = 0; c < 2; c++) {
                int row = 32 * wk + 16 * mt + ln, k = 32 * c + 8 * lg;
                A[0][mt][c] = frag(buf[0], row, k);
                A[1][mt][c] = frag(buf[1], row, k);
            }
        #pragma unroll
        for (int nt = 0; nt < 2; nt++) {
            #pragma unroll
            for (int mt = 0; mt < 2; mt++) {
                f32x4 acc = {0.f, 0.f, 0.f, 0.f};
                acc = MFMA(A[0][mt][0], Bq[0][nt][0], acc);
                acc = MFMA(A[0][mt][1], Bq[0][nt][1], acc);
                acc = MFMA(A[0][mt][0], Bq[1][nt][0], acc);
                acc = MFMA(A[0][mt][1], Bq[1][nt][1], acc);
                acc = MFMA(A[1][mt][0], Bq[0][nt][0], acc);
                acc = MFMA(A[1][mt][1], Bq[0][nt][1], acc);
                #pragma unroll
                for (int r = 0; r < 4; r++) {
                    int kl = 32 * wk + 16 * mt + 4 * lg + r;
                    float s = acc[r] * F[ixi[kl]][qx_[nt]] * F[iyi[kl]][qy_[nt]] * SCALE;
                    float e = __expf(s);
                    l[nt]  += e;
                    a0[nt] += e * v0s[kl];
                }
            }
        }
        __syncthreads();
    }
    // sum across lane-groups (keys) within the wave
    #pragma unroll
    for (int d = 16; d < 64; d <<= 1) {
        #pragma unroll
        for (int nt = 0; nt < 2; nt++) {
            l[nt]  += __shfl_xor(l[nt], d);
            a0[nt] += __shfl_xor(a0[nt], d);
        }
    }
    if (lane < 16) {
        #pragma unroll
        for (int nt = 0; nt < 2; nt++) {
            int ql = 32 * wq + 16 * nt + ln;
            red[wk][ql][0] = l[nt];
            red[wk][ql][1] = a0[nt];
        }
    }
    __syncthreads();
    if (tid < 64) {
        size_t o = (size_t)g * BHN + hb + q0 + tid;
        rowPl[o] = red[0][tid][0] + red[1][tid][0];
        rowPa[o] = red[0][tid][1] + red[1][tid][1];
    }
}

// rowfinal: den = sum_g l;  x0 = (sum_g a0) / den.
__global__ __launch_bounds__(256)
void rowfinal_kernel(const float* __restrict__ rowPl, const float* __restrict__ rowPa,
                     float* __restrict__ denomo, float* __restrict__ x0o)
{
    int i = blockIdx.x * 256 + threadIdx.x;
    if (i >= BHN) return;
    float L = 0.f, A = 0.f;
    #pragma unroll
    for (int g = 0; g < G; g++) {
        L += rowPl[(size_t)g * BHN + i];
        A += rowPa[(size_t)g * BHN + i];
    }
    denomo[i] = L;
    x0o[i] = A / L;
}

// ---------------------------------------------------------------------------
// Kernel D: column pass over a 576-query chunk.
// x1_partial[k] = sum_{q in chunk} exp(s) * v1[q]/denom[q].  grid (36,16,G).
// ---------------------------------------------------------------------------
__global__ __launch_bounds__(256)
void colpass_kernel(const ushort* __restrict__ Q1, const ushort* __restrict__ Q2,
                    const ushort* __restrict__ K1, const ushort* __restrict__ K2,
                    const int* __restrict__ idxbuf, const float* __restrict__ value1,
                    const float* __restrict__ denomo, float* __restrict__ colP)
{
    const int bh = blockIdx.y, b = bh >> 3;
    const int kt0 = blockIdx.x * 64;
    const int g = blockIdx.z;
    const size_t hb = (size_t)bh * N;

    __shared__ alignas(16) ushort buf[2][64][72];   // K staging, then Q stream
    __shared__ float F[48][49];
    __shared__ int ixi[64], iyi[64];
    __shared__ float wvs[64];
    __shared__ int qxs[64], qys[64];
    __shared__ float redx[2][64];

    const int tid = threadIdx.x;
    const int lane = tid & 63, w = tid >> 6;
    const int wk = w >> 1, wq = w & 1;
    const int lg = lane >> 4, ln = lane & 15;

    for (int i = tid; i < 48 * 48; i += 256) {
        int a = i / 48, j = i % 48;
        float lj = -1.0f + (2.0f / 47.0f) * (float)j;
        float dd = lj - (float)a;
        F[a][j] = __expf(-dd * dd * INV2S2);
    }
    stage_tile(K1 + (hb + kt0) * 64, buf[0], tid);
    stage_tile(K2 + (hb + kt0) * 64, buf[1], tid);
    if (tid < 64) {
        int v = idxbuf[hb + kt0 + tid];
        ixi[tid] = v % 48; iyi[tid] = v / 48;
    }
    __syncthreads();

    short8 A[2][2][2];
    #pragma unroll
    for (int mt = 0; mt < 2; mt++)
        #pragma unroll
        for (int c = 0; c < 2; c++) {
            int row = 32 * wk + 16 * mt + ln, k = 32 * c + 8 * lg;
            A[0][mt][c] = frag(buf[0], row, k);
            A[1][mt][c] = frag(buf[1], row, k);
        }
    int ixr[2][4], iyr[2][4];
    #pragma unroll
    for (int mt = 0; mt < 2; mt++)
        #pragma unroll
        for (int r = 0; r < 4; r++) {
            int kl = 32 * wk + 16 * mt + 4 * lg + r;
            ixr[mt][r] = ixi[kl]; iyr[mt][r] = iyi[kl];
        }
    __syncthreads();                      // K consumed; buf free for Q

    float acc1[2][4] = {};

    for (int qt = g * CHUNK; qt < (g + 1) * CHUNK; qt += 64) {
        stage_tile(Q1 + (hb + qt) * 64, buf[0], tid);
        stage_tile(Q2 + (hb + qt) * 64, buf[1], tid);
        if (tid < 64) {
            int qg = qt + tid;
            wvs[tid] = value1[(size_t)b * N + qg] / denomo[hb + qg];
            qxs[tid] = qg % 48; qys[tid] = qg / 48;
        }
        __syncthreads();
        #pragma unroll
        for (int nt = 0; nt < 2; nt++) {
            short8 Bv0[2], Bv1[2];
            #pragma unroll
            for (int c = 0; c < 2; c++) {
                int row = 32 * wq + 16 * nt + ln, k = 32 * c + 8 * lg;
                Bv0[c] = frag(buf[0], row, k);
                Bv1[c] = frag(buf[1], row, k);
            }
            int qi = 32 * wq + 16 * nt + ln;
            int qx = qxs[qi], qy = qys[qi];
            float wq_ = wvs[qi];
            #pragma unroll
            for (int mt = 0; mt < 2; mt++) {
                f32x4 acc = {0.f, 0.f, 0.f, 0.f};
                acc = MFMA(A[0][mt][0], Bv0[0], acc);
                acc = MFMA(A[0][mt][1], Bv0[1], acc);
                acc = MFMA(A[0][mt][0], Bv1[0], acc);
                acc = MFMA(A[0][mt][1], Bv1[1], acc);
                acc = MFMA(A[1][mt][0], Bv0[0], acc);
                acc = MFMA(A[1][mt][1], Bv0[1], acc);
                #pragma unroll
                for (int r = 0; r < 4; r++) {
                    float s = acc[r] * F[ixr[mt][r]][qx] * F[iyr[mt][r]][qy] * SCALE;
                    acc1[mt][r] += __expf(s) * wq_;
                }
            }
        }
        __syncthreads();
    }
    #pragma unroll
    for (int d = 1; d < 16; d <<= 1)
        #pragma unroll
        for (int mt = 0; mt < 2; mt++)
            #pragma unroll
            for (int r = 0; r < 4; r++)
                acc1[mt][r] += __shfl_xor(acc1[mt][r], d);
    if (ln == 0) {
        #pragma unroll
        for (int mt = 0; mt < 2; mt++)
            #pragma unroll
            for (int r = 0; r < 4; r++)
                redx[wq][32 * wk + 16 * mt + 4 * lg + r] = acc1[mt][r];
    }
    __syncthreads();
    if (tid < 64)
        colP[(size_t)g * BHN + hb + kt0 + tid] = redx[0][tid] + redx[1][tid];
}

// colfinal: x1 = sum_g partials.
__global__ __launch_bounds__(256)
void colfinal_kernel(const float* __restrict__ colP, float* __restrict__ x1o)
{
    int i = blockIdx.x * 256 + threadIdx.x;
    if (i >= BHN) return;
    float X = 0.f;
    #pragma unroll
    for (int g = 0; g < G; g++) X += colP[(size_t)g * BHN + i];
    x1o[i] = X;
}

// ---------------------------------------------------------------------------
// Kernel E: out[b,q,k] = (1/8) * sum_h x0[b,h,q] * x1[b,h,k]   (float4 stores)
// ---------------------------------------------------------------------------
__global__ __launch_bounds__(256)
void outer_kernel(const float* __restrict__ x0, const float* __restrict__ x1,
                  float* __restrict__ out)
{
    const int b = blockIdx.z;
    const int q0 = blockIdx.y * 32, k0 = blockIdx.x * 32;
    __shared__ float x0s[8][32];
    __shared__ float x1s[8][32];
    const int tid = threadIdx.x;
    {
        int hh = tid >> 5, i = tid & 31;
        x0s[hh][i] = x0[(size_t)(b * 8 + hh) * N + q0 + i];
        x1s[hh][i] = x1[(size_t)(b * 8 + hh) * N + k0 + i];
    }
    __syncthreads();
    const int row = tid >> 3, c4 = (tid & 7) * 4;
    float4 a = {0.f, 0.f, 0.f, 0.f};
    #pragma unroll
    for (int hh = 0; hh < 8; hh++) {
        float s = x0s[hh][row];
        a.x += s * x1s[hh][c4 + 0];
        a.y += s * x1s[hh][c4 + 1];
        a.z += s * x1s[hh][c4 + 2];
        a.w += s * x1s[hh][c4 + 3];
    }
    a.x *= 0.125f; a.y *= 0.125f; a.z *= 0.125f; a.w *= 0.125f;
    *(float4*)(out + (size_t)b * N * N + (size_t)(q0 + row) * N + k0 + c4) = a;
}

} // namespace

extern "C" void kernel_launch(void* const* d_in, const int* in_sizes, int n_in,
                              void* d_out, int out_size, void* d_ws, size_t ws_size,
                              hipStream_t stream) {
    const float* qin = (const float*)d_in[0];
    const float* kin = (const float*)d_in[1];
    const float* v0  = (const float*)d_in[2];
    const float* v1  = (const float*)d_in[3];
    const float* Wq  = (const float*)d_in[4];
    const float* bq  = (const float*)d_in[5];
    const float* Wk  = (const float*)d_in[6];
    const float* bk  = (const float*)d_in[7];
    float* out = (float*)d_out;

    // d_out layout: 6 bf16-split arrays (28.3 MB) + G-partials tail (2.9 MB),
    // all dead by the time outer_kernel overwrites the whole buffer.
    const size_t ARR = (size_t)BH * N * DK;   // 2359296 ushorts per split array
    ushort* Q1 = (ushort*)d_out;
    ushort* Q2 = Q1 + ARR;
    ushort* Q3 = Q2 + ARR;
    ushort* K1 = Q3 + ARR;
    ushort* K2 = K1 + ARR;
    ushort* K3 = K2 + ARR;
    float* tail = (float*)(K3 + ARR);
    float* argV  = tail;                       // [G][BHN]
    int*   argQ  = (int*)(tail + (size_t)G * BHN);
    float* rowPl = tail + 2 * (size_t)G * BHN;
    float* rowPa = tail + 3 * (size_t)G * BHN;
    float* colP  = tail + 4 * (size_t)G * BHN;

    // small finalized stats in ws (outer reads ONLY ws)
    int*   idxb = (int*)d_ws;
    float* den  = (float*)(idxb + (size_t)BHN);
    float* x0b  = den + (size_t)BHN;
    float* x1b  = x0b + (size_t)BHN;

    const int RB = (BHN + 255) / 256;   // 144 blocks for elementwise finalizers

    proj_kernel      <<<dim3(8, 72, 2),  dim3(16, 16), 0, stream>>>(qin, kin, Wq, bq, Wk, bk,
                                                                    Q1, Q2, Q3, K1, K2, K3);
    argmax_kernel    <<<dim3(36, 16, G), dim3(256),    0, stream>>>(Q1, Q2, Q3, K1, K2, K3,
                                                                    argV, argQ);
    argcombine_kernel<<<dim3(RB),        dim3(256),    0, stream>>>(argV, argQ, idxb);
    rowpass_kernel   <<<dim3(36, 16, G), dim3(256),    0, stream>>>(Q1, Q2, K1, K2, idxb, v0,
                                                                    rowPl, rowPa);
    rowfinal_kernel  <<<dim3(RB),        dim3(256),    0, stream>>>(rowPl, rowPa, den, x0b);
    colpass_kernel   <<<dim3(36, 16, G), dim3(256),    0, stream>>>(Q1, Q2, K1, K2, idxb, v1,
                                                                    den, colP);
    colfinal_kernel  <<<dim3(RB),        dim3(256),    0, stream>>>(colP, x1b);
    outer_kernel     <<<dim3(72, 72, 2), dim3(256),    0, stream>>>(x0b, x1b, out);
}

// Round 6
// 289.309 us; speedup vs baseline: 1.2245x; 1.0759x over previous
//
#include <hip/hip_runtime.h>
#include <cstddef>
#include <cstdint>

namespace {

constexpr int S = 48;
constexpr int N = S * S;        // 2304 positions
constexpr int D = 512;          // d_model
constexpr int DK = 64;          // head dim
constexpr int B = 2;
constexpr int BH = 16;          // b*heads
constexpr int BHN = BH * N;     // 36864
constexpr int G = 4;            // reduction-dim split factor
constexpr int CHUNK = N / G;    // 576 positions = 9 tiles of 64
constexpr float SCALE = 0.125f;     // 1/sqrt(DK)
constexpr float INV2S2 = 0.02f;     // 1/(2*sigma^2), sigma=5

typedef __attribute__((ext_vector_type(8))) short short8;
typedef __attribute__((ext_vector_type(8))) unsigned short ushort8v;
typedef __attribute__((ext_vector_type(4))) float f32x4;

#define MFMA(a, b, c) __builtin_amdgcn_mfma_f32_16x16x32_bf16((a), (b), (c), 0, 0, 0)

struct U3 { ushort a, b, c; };

// 3-way bf16 split: x ~= a + b + c (each RNE bf16), residual ~2^-26|x|
__device__ __forceinline__ U3 split3(float x)
{
    U3 u;
    uint b1 = __float_as_uint(x);
    uint r1 = (b1 + (0x7FFFu + ((b1 >> 16) & 1u))) & 0xFFFF0000u;
    u.a = (ushort)(r1 >> 16);
    float d1 = x - __uint_as_float(r1);                 // exact
    uint b2 = __float_as_uint(d1);
    uint r2 = (b2 + (0x7FFFu + ((b2 >> 16) & 1u))) & 0xFFFF0000u;
    u.b = (ushort)(r2 >> 16);
    float d2 = d1 - __uint_as_float(r2);                // exact
    uint b3 = __float_as_uint(d2);
    u.c = (ushort)((b3 + (0x7FFFu + ((b3 >> 16) & 1u))) >> 16);
    return u;
}

// Copy a 64x64 ushort tile global -> LDS [64][72] (16B chunks, coalesced).
__device__ __forceinline__ void stage_tile(const ushort* __restrict__ g,
                                           ushort (*L)[72], int tid)
{
    #pragma unroll
    for (int it = 0; it < 2; it++) {
        int f = tid + 256 * it;
        int row = f >> 3, c8 = (f & 7) * 8;
        *(ushort8v*)&L[row][c8] = *(const ushort8v*)&g[(size_t)row * 64 + c8];
    }
}

__device__ __forceinline__ short8 frag(const ushort (*L)[72], int row, int k)
{
    return *(const short8*)&L[row][k];
}

// Swizzled [64][64] LDS tile helpers (16B aligned, ~2-way max conflicts)
__device__ __forceinline__ void stage_swz(ushort* __restrict__ L,
                                          const ushort* __restrict__ g, int tid)
{
    #pragma unroll
    for (int it = 0; it < 2; it++) {
        int f = tid + 256 * it;
        int row = f >> 3, c8 = (f & 7) * 8;
        int off = (row * 64 + c8) ^ ((row & 7) << 3);
        *(ushort8v*)&L[off] = *(const ushort8v*)&g[(size_t)row * 64 + c8];
    }
}
__device__ __forceinline__ short8 frag_swz(const ushort* __restrict__ L, int row, int k)
{
    int off = (row * 64 + k) ^ ((row & 7) << 3);
    return *(const short8*)&L[off];
}

// ---------------------------------------------------------------------------
// Kernel S: split inputs/weights to 3-way bf16 arrays.
//  z=0: qin -> XQ[(b*8+kh)][npos][64]   z=1: kin -> XK[...]
//  z=2: Wq,Wk -> W[(inp*8+kh)][n][64]
// ---------------------------------------------------------------------------
__global__ __launch_bounds__(256)
void split_kernel(const float* __restrict__ qin, const float* __restrict__ kin,
                  const float* __restrict__ Wq, const float* __restrict__ Wk,
                  ushort* __restrict__ XQ1, ushort* __restrict__ XQ2, ushort* __restrict__ XQ3,
                  ushort* __restrict__ XK1, ushort* __restrict__ XK2, ushort* __restrict__ XK3,
                  ushort* __restrict__ W1, ushort* __restrict__ W2, ushort* __restrict__ W3)
{
    const int z = blockIdx.y;
    const int gid = blockIdx.x * 256 + threadIdx.x;
    const float* src;
    ushort *O1, *O2, *O3;
    size_t dst, soff;
    if (z < 2) {
        int m = gid >> 6, c = gid & 63;
        int b = (m >= N) ? 1 : 0;
        int npos = m - b * N;
        src = z ? kin : qin;
        if (z) { O1 = XK1; O2 = XK2; O3 = XK3; }
        else   { O1 = XQ1; O2 = XQ2; O3 = XQ3; }
        soff = (size_t)m * D + c * 8;
        dst = ((size_t)(b * 8 + (c >> 3)) * N + npos) * 64 + (c & 7) * 8;
    } else {
        if (gid >= 65536) return;
        int r = gid >> 6, c = gid & 63;
        int inp = r >> 9, n = r & 511;
        src = inp ? Wk : Wq;
        O1 = W1; O2 = W2; O3 = W3;
        soff = (size_t)n * D + c * 8;
        dst = ((size_t)(inp * 8 + (c >> 3)) * 512 + n) * 64 + (c & 7) * 8;
    }
    ushort8v u1, u2, u3;
    #pragma unroll
    for (int j = 0; j < 8; j++) {
        U3 t = split3(src[soff + j]);
        u1[j] = t.a; u2[j] = t.b; u3[j] = t.c;
    }
    *(ushort8v*)&O1[dst] = u1;
    *(ushort8v*)&O2[dst] = u2;
    *(ushort8v*)&O3[dst] = u3;
}

// ---------------------------------------------------------------------------
// Kernel A: MFMA projection.  C[m,n] = sum_k X[m,k]*W[n,k] (+bias), 3-split
// inputs, 6 products -> fp32-grade accuracy.  Output re-split3 to per-head
// layout.  Grid (8 heads, 72 m-tiles); 64x64 tile; wave = 32x32.
// ---------------------------------------------------------------------------
__global__ __launch_bounds__(256)
void proj_kernel(const ushort* __restrict__ X1, const ushort* __restrict__ X2,
                 const ushort* __restrict__ X3, const ushort* __restrict__ Wp1,
                 const ushort* __restrict__ Wp2, const ushort* __restrict__ Wp3,
                 const float* __restrict__ bias,
                 ushort* __restrict__ O1, ushort* __restrict__ O2, ushort* __restrict__ O3)
{
    const int tid = threadIdx.x;
    const int lane = tid & 63, w = tid >> 6;
    const int wm = w >> 1, wn = w & 1;
    const int lg = lane >> 4, ln = lane & 15;
    const int hsel = blockIdx.x;          // head 0..7
    const int my = blockIdx.y;            // 0..71
    const int b = my / 36;
    const int npos0 = (my % 36) * 64;

    __shared__ alignas(16) ushort bufX[3][64 * 64];
    __shared__ alignas(16) ushort bufW[3][64 * 64];

    f32x4 acc[2][2];
    #pragma unroll
    for (int mt = 0; mt < 2; mt++)
        #pragma unroll
        for (int nt = 0; nt < 2; nt++) acc[mt][nt] = (f32x4){0.f, 0.f, 0.f, 0.f};

    for (int kh = 0; kh < 8; kh++) {
        stage_swz(bufX[0], X1 + ((size_t)(b * 8 + kh) * N + npos0) * 64, tid);
        stage_swz(bufX[1], X2 + ((size_t)(b * 8 + kh) * N + npos0) * 64, tid);
        stage_swz(bufX[2], X3 + ((size_t)(b * 8 + kh) * N + npos0) * 64, tid);
        stage_swz(bufW[0], Wp1 + ((size_t)kh * 512 + hsel * 64) * 64, tid);
        stage_swz(bufW[1], Wp2 + ((size_t)kh * 512 + hsel * 64) * 64, tid);
        stage_swz(bufW[2], Wp3 + ((size_t)kh * 512 + hsel * 64) * 64, tid);
        __syncthreads();

        short8 A[3][2][2], Bv[3][2][2];
        #pragma unroll
        for (int mt = 0; mt < 2; mt++)
            #pragma unroll
            for (int c = 0; c < 2; c++) {
                int row = 32 * wm + 16 * mt + ln, k = 32 * c + 8 * lg;
                A[0][mt][c] = frag_swz(bufX[0], row, k);
                A[1][mt][c] = frag_swz(bufX[1], row, k);
                A[2][mt][c] = frag_swz(bufX[2], row, k);
            }
        #pragma unroll
        for (int nt = 0; nt < 2; nt++)
            #pragma unroll
            for (int c = 0; c < 2; c++) {
                int row = 32 * wn + 16 * nt + ln, k = 32 * c + 8 * lg;
                Bv[0][nt][c] = frag_swz(bufW[0], row, k);
                Bv[1][nt][c] = frag_swz(bufW[1], row, k);
                Bv[2][nt][c] = frag_swz(bufW[2], row, k);
            }
        #pragma unroll
        for (int mt = 0; mt < 2; mt++)
            #pragma unroll
            for (int nt = 0; nt < 2; nt++) {
                f32x4 a = acc[mt][nt];
                a = MFMA(A[0][mt][0], Bv[0][nt][0], a);
                a = MFMA(A[0][mt][1], Bv[0][nt][1], a);
                a = MFMA(A[0][mt][0], Bv[1][nt][0], a);
                a = MFMA(A[0][mt][1], Bv[1][nt][1], a);
                a = MFMA(A[1][mt][0], Bv[0][nt][0], a);
                a = MFMA(A[1][mt][1], Bv[0][nt][1], a);
                a = MFMA(A[0][mt][0], Bv[2][nt][0], a);
                a = MFMA(A[0][mt][1], Bv[2][nt][1], a);
                a = MFMA(A[1][mt][0], Bv[1][nt][0], a);
                a = MFMA(A[1][mt][1], Bv[1][nt][1], a);
                a = MFMA(A[2][mt][0], Bv[0][nt][0], a);
                a = MFMA(A[2][mt][1], Bv[0][nt][1], a);
                acc[mt][nt] = a;
            }
        __syncthreads();
    }
    // epilogue: stage C through LDS, re-split3, coalesced per-head writes
    float* Cs = (float*)&bufX[0][0];      // [64][68]
    #pragma unroll
    for (int mt = 0; mt < 2; mt++)
        #pragma unroll
        for (int nt = 0; nt < 2; nt++)
            #pragma unroll
            for (int r = 0; r < 4; r++)
                Cs[(32 * wm + 16 * mt + 4 * lg + r) * 68 + 32 * wn + 16 * nt + ln] =
                    acc[mt][nt][r];
    __syncthreads();
    const int row = tid >> 2, c0 = (tid & 3) * 16;
    size_t dst = ((size_t)(b * 8 + hsel) * N + npos0 + row) * 64 + c0;
    #pragma unroll
    for (int half = 0; half < 2; half++) {
        ushort8v u1, u2, u3;
        #pragma unroll
        for (int j = 0; j < 8; j++) {
            int cc = c0 + half * 8 + j;
            float v = Cs[row * 68 + cc] + bias[hsel * 64 + cc];
            U3 t = split3(v);
            u1[j] = t.a; u2[j] = t.b; u3[j] = t.c;
        }
        *(ushort8v*)&O1[dst + half * 8] = u1;
        *(ushort8v*)&O2[dst + half * 8] = u2;
        *(ushort8v*)&O3[dst + half * 8] = u3;
    }
}

// ---------------------------------------------------------------------------
// Kernel B: per-key argmax over a 576-query CHUNK of raw scores.  3-split,
// 6 MFMA products.  grid (36 ktiles, 16 bh, G chunks); partial best written
// to argV/argQ[g].  Tie-break: lowest q (ascending scan + strict >).
// ---------------------------------------------------------------------------
__global__ __launch_bounds__(256)
void argmax_kernel(const ushort* __restrict__ Q1, const ushort* __restrict__ Q2,
                   const ushort* __restrict__ Q3, const ushort* __restrict__ K1,
                   const ushort* __restrict__ K2, const ushort* __restrict__ K3,
                   float* __restrict__ argV, int* __restrict__ argQ)
{
    const int bh = blockIdx.y;
    const int kt0 = blockIdx.x * 64;
    const int g = blockIdx.z;
    const size_t hb = (size_t)bh * N;

    __shared__ alignas(16) ushort buf[3][64][72];   // K staging, then Q stream
    __shared__ float redv[2][64];
    __shared__ int   redq[2][64];

    const int tid = threadIdx.x;
    const int lane = tid & 63, w = tid >> 6;
    const int wk = w >> 1, wq = w & 1;
    const int lg = lane >> 4, ln = lane & 15;

    stage_tile(K1 + (hb + kt0) * 64, buf[0], tid);
    stage_tile(K2 + (hb + kt0) * 64, buf[1], tid);
    stage_tile(K3 + (hb + kt0) * 64, buf[2], tid);
    __syncthreads();

    short8 A[3][2][2];                   // [comp][mt][chunk]
    #pragma unroll
    for (int mt = 0; mt < 2; mt++)
        #pragma unroll
        for (int c = 0; c < 2; c++) {
            int row = 32 * wk + 16 * mt + ln, k = 32 * c + 8 * lg;
            A[0][mt][c] = frag(buf[0], row, k);
            A[1][mt][c] = frag(buf[1], row, k);
            A[2][mt][c] = frag(buf[2], row, k);
        }
    __syncthreads();                      // K fully consumed; buf now free

    float bestv[2][4];
    int   bestq[2][4];
    #pragma unroll
    for (int mt = 0; mt < 2; mt++)
        #pragma unroll
        for (int r = 0; r < 4; r++) { bestv[mt][r] = -3e38f; bestq[mt][r] = 0; }

    for (int qt = g * CHUNK; qt < (g + 1) * CHUNK; qt += 64) {
        stage_tile(Q1 + (hb + qt) * 64, buf[0], tid);
        stage_tile(Q2 + (hb + qt) * 64, buf[1], tid);
        stage_tile(Q3 + (hb + qt) * 64, buf[2], tid);
        __syncthreads();
        #pragma unroll
        for (int nt = 0; nt < 2; nt++) {
            short8 Bv0[2], Bv1[2], Bv2[2];
            #pragma unroll
            for (int c = 0; c < 2; c++) {
                int row = 32 * wq + 16 * nt + ln, k = 32 * c + 8 * lg;
                Bv0[c] = frag(buf[0], row, k);
                Bv1[c] = frag(buf[1], row, k);
                Bv2[c] = frag(buf[2], row, k);
            }
            #pragma unroll
            for (int mt = 0; mt < 2; mt++) {
                f32x4 acc = {0.f, 0.f, 0.f, 0.f};
                acc = MFMA(A[0][mt][0], Bv0[0], acc);
                acc = MFMA(A[0][mt][1], Bv0[1], acc);
                acc = MFMA(A[0][mt][0], Bv1[0], acc);
                acc = MFMA(A[0][mt][1], Bv1[1], acc);
                acc = MFMA(A[1][mt][0], Bv0[0], acc);
                acc = MFMA(A[1][mt][1], Bv0[1], acc);
                acc = MFMA(A[0][mt][0], Bv2[0], acc);
                acc = MFMA(A[0][mt][1], Bv2[1], acc);
                acc = MFMA(A[1][mt][0], Bv1[0], acc);
                acc = MFMA(A[1][mt][1], Bv1[1], acc);
                acc = MFMA(A[2][mt][0], Bv0[0], acc);
                acc = MFMA(A[2][mt][1], Bv0[1], acc);
                int q = qt + 32 * wq + 16 * nt + ln;
                #pragma unroll
                for (int r = 0; r < 4; r++)
                    if (acc[r] > bestv[mt][r]) { bestv[mt][r] = acc[r]; bestq[mt][r] = q; }
            }
        }
        __syncthreads();
    }
    #pragma unroll
    for (int d = 1; d < 16; d <<= 1) {
        #pragma unroll
        for (int mt = 0; mt < 2; mt++)
            #pragma unroll
            for (int r = 0; r < 4; r++) {
                float ov = __shfl_xor(bestv[mt][r], d);
                int   oq = __shfl_xor(bestq[mt][r], d);
                if (ov > bestv[mt][r] || (ov == bestv[mt][r] && oq < bestq[mt][r])) {
                    bestv[mt][r] = ov; bestq[mt][r] = oq;
                }
            }
    }
    if (ln == 0) {
        #pragma unroll
        for (int mt = 0; mt < 2; mt++)
            #pragma unroll
            for (int r = 0; r < 4; r++) {
                int key = 32 * wk + 16 * mt + 4 * lg + r;
                redv[wq][key] = bestv[mt][r];
                redq[wq][key] = bestq[mt][r];
            }
    }
    __syncthreads();
    if (tid < 64) {
        float va = redv[0][tid], vb = redv[1][tid];
        int   qa = redq[0][tid], qb = redq[1][tid];
        int   bi = (vb > va || (vb == va && qb < qa)) ? qb : qa;
        float bv = fmaxf(va, vb);
        size_t o = (size_t)g * BHN + hb + kt0 + tid;
        argV[o] = bv;
        argQ[o] = bi;
    }
}

// Combine G partial argmaxes (ascending g keeps lowest q on ties).
__global__ __launch_bounds__(256)
void argcombine_kernel(const float* __restrict__ argV, const int* __restrict__ argQ,
                       int* __restrict__ idxout)
{
    int i = blockIdx.x * 256 + threadIdx.x;
    if (i >= BHN) return;
    float bv = argV[i]; int bq = argQ[i];
    #pragma unroll
    for (int g = 1; g < G; g++) {
        float v = argV[(size_t)g * BHN + i];
        int   q = argQ[(size_t)g * BHN + i];
        if (v > bv) { bv = v; bq = q; }
    }
    idxout[i] = bq;
}

// ---------------------------------------------------------------------------
// Kernel C: row pass over a 576-key chunk (softmax over k, no max subtract --
// scores bounded).  Partial l, a0 written per chunk.  grid (36 qtiles,16,G).
// ---------------------------------------------------------------------------
__global__ __launch_bounds__(256)
void rowpass_kernel(const ushort* __restrict__ Q1, const ushort* __restrict__ Q2,
                    const ushort* __restrict__ K1, const ushort* __restrict__ K2,
                    const int* __restrict__ idxbuf, const float* __restrict__ value0,
                    float* __restrict__ rowPl, float* __restrict__ rowPa)
{
    const int bh = blockIdx.y, b = bh >> 3;
    const int q0 = blockIdx.x * 64;
    const int g = blockIdx.z;
    const size_t hb = (size_t)bh * N;

    __shared__ alignas(16) ushort buf[2][64][72];   // Q staging, then K stream
    __shared__ float F[48][49];
    __shared__ int ixi[64], iyi[64];
    __shared__ float v0s[64];
    __shared__ float red[2][64][2];

    const int tid = threadIdx.x;
    const int lane = tid & 63, w = tid >> 6;
    const int wk = w >> 1, wq = w & 1;
    const int lg = lane >> 4, ln = lane & 15;

    for (int i = tid; i < 48 * 48; i += 256) {
        int a = i / 48, j = i % 48;
        float lj = -1.0f + (2.0f / 47.0f) * (float)j;
        float dd = lj - (float)a;
        F[a][j] = __expf(-dd * dd * INV2S2);
    }
    stage_tile(Q1 + (hb + q0) * 64, buf[0], tid);
    stage_tile(Q2 + (hb + q0) * 64, buf[1], tid);
    __syncthreads();

    short8 Bq[2][2][2];                  // [comp][nt][chunk]
    int qx_[2], qy_[2];
    #pragma unroll
    for (int nt = 0; nt < 2; nt++) {
        #pragma unroll
        for (int c = 0; c < 2; c++) {
            int row = 32 * wq + 16 * nt + ln, k = 32 * c + 8 * lg;
            Bq[0][nt][c] = frag(buf[0], row, k);
            Bq[1][nt][c] = frag(buf[1], row, k);
        }
        int qq = q0 + 32 * wq + 16 * nt + ln;
        qx_[nt] = qq % 48; qy_[nt] = qq / 48;
    }
    __syncthreads();                      // Q consumed; buf free for K

    float l[2] = {0.f, 0.f}, a0[2] = {0.f, 0.f};

    for (int kt = g * CHUNK; kt < (g + 1) * CHUNK; kt += 64) {
        stage_tile(K1 + (hb + kt) * 64, buf[0], tid);
        stage_tile(K2 + (hb + kt) * 64, buf[1], tid);
        if (tid < 64) {
            int v = idxbuf[hb + kt + tid];
            ixi[tid] = v % 48; iyi[tid] = v / 48;
            v0s[tid] = value0[(size_t)b * N + kt + tid];
        }
        __syncthreads();
        short8 A[2][2][2];               // [comp][mt][chunk]
        #pragma unroll
        for (int mt = 0; mt < 2; mt++)
            #pragma unroll
            for (int c = 0; c < 2; c++) {
                int row = 32 * wk + 16 * mt + ln, k = 32 * c + 8 * lg;
                A[0][mt][c] = frag(buf[0], row, k);
                A[1][mt][c] = frag(buf[1], row, k);
            }
        #pragma unroll
        for (int nt = 0; nt < 2; nt++) {
            #pragma unroll
            for (int mt = 0; mt < 2; mt++) {
                f32x4 acc = {0.f, 0.f, 0.f, 0.f};
                acc = MFMA(A[0][mt][0], Bq[0][nt][0], acc);
                acc = MFMA(A[0][mt][1], Bq[0][nt][1], acc);
                acc = MFMA(A[0][mt][0], Bq[1][nt][0], acc);
                acc = MFMA(A[0][mt][1], Bq[1][nt][1], acc);
                acc = MFMA(A[1][mt][0], Bq[0][nt][0], acc);
                acc = MFMA(A[1][mt][1], Bq[0][nt][1], acc);
                #pragma unroll
                for (int r = 0; r < 4; r++) {
                    int kl = 32 * wk + 16 * mt + 4 * lg + r;
                    float s = acc[r] * F[ixi[kl]][qx_[nt]] * F[iyi[kl]][qy_[nt]] * SCALE;
                    float e = __expf(s);
                    l[nt]  += e;
                    a0[nt] += e * v0s[kl];
                }
            }
        }
        __syncthreads();
    }
    // sum across lane-groups (keys) within the wave
    #pragma unroll
    for (int d = 16; d < 64; d <<= 1) {
        #pragma unroll
        for (int nt = 0; nt < 2; nt++) {
            l[nt]  += __shfl_xor(l[nt], d);
            a0[nt] += __shfl_xor(a0[nt], d);
        }
    }
    if (lane < 16) {
        #pragma unroll
        for (int nt = 0; nt < 2; nt++) {
            int ql = 32 * wq + 16 * nt + ln;
            red[wk][ql][0] = l[nt];
            red[wk][ql][1] = a0[nt];
        }
    }
    __syncthreads();
    if (tid < 64) {
        size_t o = (size_t)g * BHN + hb + q0 + tid;
        rowPl[o] = red[0][tid][0] + red[1][tid][0];
        rowPa[o] = red[0][tid][1] + red[1][tid][1];
    }
}

// rowfinal: den = sum_g l;  x0 = (sum_g a0) / den.
__global__ __launch_bounds__(256)
void rowfinal_kernel(const float* __restrict__ rowPl, const float* __restrict__ rowPa,
                     float* __restrict__ denomo, float* __restrict__ x0o)
{
    int i = blockIdx.x * 256 + threadIdx.x;
    if (i >= BHN) return;
    float L = 0.f, A = 0.f;
    #pragma unroll
    for (int g = 0; g < G; g++) {
        L += rowPl[(size_t)g * BHN + i];
        A += rowPa[(size_t)g * BHN + i];
    }
    denomo[i] = L;
    x0o[i] = A / L;
}

// ---------------------------------------------------------------------------
// Kernel D: column pass over a 576-query chunk.
// x1_partial[k] = sum_{q in chunk} exp(s) * v1[q]/denom[q].  grid (36,16,G).
// ---------------------------------------------------------------------------
__global__ __launch_bounds__(256)
void colpass_kernel(const ushort* __restrict__ Q1, const ushort* __restrict__ Q2,
                    const ushort* __restrict__ K1, const ushort* __restrict__ K2,
                    const int* __restrict__ idxbuf, const float* __restrict__ value1,
                    const float* __restrict__ denomo, float* __restrict__ colP)
{
    const int bh = blockIdx.y, b = bh >> 3;
    const int kt0 = blockIdx.x * 64;
    const int g = blockIdx.z;
    const size_t hb = (size_t)bh * N;

    __shared__ alignas(16) ushort buf[2][64][72];   // K staging, then Q stream
    __shared__ float F[48][49];
    __shared__ int ixi[64], iyi[64];
    __shared__ float wvs[64];
    __shared__ int qxs[64], qys[64];
    __shared__ float redx[2][64];

    const int tid = threadIdx.x;
    const int lane = tid & 63, w = tid >> 6;
    const int wk = w >> 1, wq = w & 1;
    const int lg = lane >> 4, ln = lane & 15;

    for (int i = tid; i < 48 * 48; i += 256) {
        int a = i / 48, j = i % 48;
        float lj = -1.0f + (2.0f / 47.0f) * (float)j;
        float dd = lj - (float)a;
        F[a][j] = __expf(-dd * dd * INV2S2);
    }
    stage_tile(K1 + (hb + kt0) * 64, buf[0], tid);
    stage_tile(K2 + (hb + kt0) * 64, buf[1], tid);
    if (tid < 64) {
        int v = idxbuf[hb + kt0 + tid];
        ixi[tid] = v % 48; iyi[tid] = v / 48;
    }
    __syncthreads();

    short8 A[2][2][2];
    #pragma unroll
    for (int mt = 0; mt < 2; mt++)
        #pragma unroll
        for (int c = 0; c < 2; c++) {
            int row = 32 * wk + 16 * mt + ln, k = 32 * c + 8 * lg;
            A[0][mt][c] = frag(buf[0], row, k);
            A[1][mt][c] = frag(buf[1], row, k);
        }
    int ixr[2][4], iyr[2][4];
    #pragma unroll
    for (int mt = 0; mt < 2; mt++)
        #pragma unroll
        for (int r = 0; r < 4; r++) {
            int kl = 32 * wk + 16 * mt + 4 * lg + r;
            ixr[mt][r] = ixi[kl]; iyr[mt][r] = iyi[kl];
        }
    __syncthreads();                      // K consumed; buf free for Q

    float acc1[2][4] = {};

    for (int qt = g * CHUNK; qt < (g + 1) * CHUNK; qt += 64) {
        stage_tile(Q1 + (hb + qt) * 64, buf[0], tid);
        stage_tile(Q2 + (hb + qt) * 64, buf[1], tid);
        if (tid < 64) {
            int qg = qt + tid;
            wvs[tid] = value1[(size_t)b * N + qg] / denomo[hb + qg];
            qxs[tid] = qg % 48; qys[tid] = qg / 48;
        }
        __syncthreads();
        #pragma unroll
        for (int nt = 0; nt < 2; nt++) {
            short8 Bv0[2], Bv1[2];
            #pragma unroll
            for (int c = 0; c < 2; c++) {
                int row = 32 * wq + 16 * nt + ln, k = 32 * c + 8 * lg;
                Bv0[c] = frag(buf[0], row, k);
                Bv1[c] = frag(buf[1], row, k);
            }
            int qi = 32 * wq + 16 * nt + ln;
            int qx = qxs[qi], qy = qys[qi];
            float wq_ = wvs[qi];
            #pragma unroll
            for (int mt = 0; mt < 2; mt++) {
                f32x4 acc = {0.f, 0.f, 0.f, 0.f};
                acc = MFMA(A[0][mt][0], Bv0[0], acc);
                acc = MFMA(A[0][mt][1], Bv0[1], acc);
                acc = MFMA(A[0][mt][0], Bv1[0], acc);
                acc = MFMA(A[0][mt][1], Bv1[1], acc);
                acc = MFMA(A[1][mt][0], Bv0[0], acc);
                acc = MFMA(A[1][mt][1], Bv0[1], acc);
                #pragma unroll
                for (int r = 0; r < 4; r++) {
                    float s = acc[r] * F[ixr[mt][r]][qx] * F[iyr[mt][r]][qy] * SCALE;
                    acc1[mt][r] += __expf(s) * wq_;
                }
            }
        }
        __syncthreads();
    }
    #pragma unroll
    for (int d = 1; d < 16; d <<= 1)
        #pragma unroll
        for (int mt = 0; mt < 2; mt++)
            #pragma unroll
            for (int r = 0; r < 4; r++)
                acc1[mt][r] += __shfl_xor(acc1[mt][r], d);
    if (ln == 0) {
        #pragma unroll
        for (int mt = 0; mt < 2; mt++)
            #pragma unroll
            for (int r = 0; r < 4; r++)
                redx[wq][32 * wk + 16 * mt + 4 * lg + r] = acc1[mt][r];
    }
    __syncthreads();
    if (tid < 64)
        colP[(size_t)g * BHN + hb + kt0 + tid] = redx[0][tid] + redx[1][tid];
}

// colfinal: x1 = sum_g partials.
__global__ __launch_bounds__(256)
void colfinal_kernel(const float* __restrict__ colP, float* __restrict__ x1o)
{
    int i = blockIdx.x * 256 + threadIdx.x;
    if (i >= BHN) return;
    float X = 0.f;
    #pragma unroll
    for (int g = 0; g < G; g++) X += colP[(size_t)g * BHN + i];
    x1o[i] = X;
}

// ---------------------------------------------------------------------------
// Kernel E: out[b,q,k] = (1/8) * sum_h x0[b,h,q] * x1[b,h,k]   (float4 stores)
// ---------------------------------------------------------------------------
__global__ __launch_bounds__(256)
void outer_kernel(const float* __restrict__ x0, const float* __restrict__ x1,
                  float* __restrict__ out)
{
    const int b = blockIdx.z;
    const int q0 = blockIdx.y * 32, k0 = blockIdx.x * 32;
    __shared__ float x0s[8][32];
    __shared__ float x1s[8][32];
    const int tid = threadIdx.x;
    {
        int hh = tid >> 5, i = tid & 31;
        x0s[hh][i] = x0[(size_t)(b * 8 + hh) * N + q0 + i];
        x1s[hh][i] = x1[(size_t)(b * 8 + hh) * N + k0 + i];
    }
    __syncthreads();
    const int row = tid >> 3, c4 = (tid & 7) * 4;
    float4 a = {0.f, 0.f, 0.f, 0.f};
    #pragma unroll
    for (int hh = 0; hh < 8; hh++) {
        float s = x0s[hh][row];
        a.x += s * x1s[hh][c4 + 0];
        a.y += s * x1s[hh][c4 + 1];
        a.z += s * x1s[hh][c4 + 2];
        a.w += s * x1s[hh][c4 + 3];
    }
    a.x *= 0.125f; a.y *= 0.125f; a.z *= 0.125f; a.w *= 0.125f;
    *(float4*)(out + (size_t)b * N * N + (size_t)(q0 + row) * N + k0 + c4) = a;
}

} // namespace

extern "C" void kernel_launch(void* const* d_in, const int* in_sizes, int n_in,
                              void* d_out, int out_size, void* d_ws, size_t ws_size,
                              hipStream_t stream) {
    const float* qin = (const float*)d_in[0];
    const float* kin = (const float*)d_in[1];
    const float* v0  = (const float*)d_in[2];
    const float* v1  = (const float*)d_in[3];
    const float* Wq  = (const float*)d_in[4];
    const float* bq  = (const float*)d_in[5];
    const float* Wk  = (const float*)d_in[6];
    const float* bk  = (const float*)d_in[7];
    float* out = (float*)d_out;

    // d_out = exactly 9 split-array slots (18*ARR bytes = out bytes):
    //   A.1 [0,3ARR)   : Q1..Q3 proj outputs (live to colpass)
    //   A.2 [3ARR,6ARR): Xk input splits (dead after projK) -> partials/idx/den
    //   B   [6ARR,9ARR): Xq input splits (dead after projQ) -> K1..K3 outputs
    const size_t ARR = (size_t)BH * N * DK;   // 2359296 ushorts
    ushort* out_u = (ushort*)d_out;
    ushort* Q1  = out_u;
    ushort* Q2  = out_u + ARR;
    ushort* Q3  = out_u + 2 * ARR;
    ushort* XK1 = out_u + 3 * ARR;
    ushort* XK2 = out_u + 4 * ARR;
    ushort* XK3 = out_u + 5 * ARR;
    ushort* XQ1 = out_u + 6 * ARR;
    ushort* XQ2 = out_u + 7 * ARR;
    ushort* XQ3 = out_u + 8 * ARR;
    ushort* K1 = XQ1;  ushort* K2 = XQ2;  ushort* K3 = XQ3;  // projK overwrites Xq

    float* tail = (float*)XK1;                 // A.2 reuse after projK (14.15 MB)
    float* argV  = tail;                       // [G][BHN]
    int*   argQ  = (int*)(tail + (size_t)G * BHN);
    float* rowPl = tail + 2 * (size_t)G * BHN;
    float* rowPa = tail + 3 * (size_t)G * BHN;
    float* colP  = tail + 4 * (size_t)G * BHN;
    int*   idxb  = (int*)(tail + 5 * (size_t)G * BHN);
    float* den   = tail + 5 * (size_t)G * BHN + BHN;

    // ws: W splits (3 MB) + x0/x1 (outer's inputs; must not live in d_out)
    const size_t WARR = (size_t)2 * 512 * 512;     // 524288 ushorts per comp
    ushort* W1 = (ushort*)d_ws;
    ushort* W2 = W1 + WARR;
    ushort* W3 = W2 + WARR;
    float* x0b = (float*)(W3 + WARR);
    float* x1b = x0b + (size_t)BHN;

    const size_t WSLICE = (size_t)8 * 512 * 64;    // per-input W-split stride

    const int RB = (BHN + 255) / 256;   // 144 blocks for elementwise finalizers

    split_kernel     <<<dim3(1152, 3),   dim3(256), 0, stream>>>(qin, kin, Wq, Wk,
                                                                 XQ1, XQ2, XQ3,
                                                                 XK1, XK2, XK3,
                                                                 W1, W2, W3);
    proj_kernel      <<<dim3(8, 72),     dim3(256), 0, stream>>>(XQ1, XQ2, XQ3,
                                                                 W1, W2, W3, bq,
                                                                 Q1, Q2, Q3);
    proj_kernel      <<<dim3(8, 72),     dim3(256), 0, stream>>>(XK1, XK2, XK3,
                                                                 W1 + WSLICE, W2 + WSLICE,
                                                                 W3 + WSLICE, bk,
                                                                 K1, K2, K3);
    argmax_kernel    <<<dim3(36, 16, G), dim3(256), 0, stream>>>(Q1, Q2, Q3, K1, K2, K3,
                                                                 argV, argQ);
    argcombine_kernel<<<dim3(RB),        dim3(256), 0, stream>>>(argV, argQ, idxb);
    rowpass_kernel   <<<dim3(36, 16, G), dim3(256), 0, stream>>>(Q1, Q2, K1, K2, idxb, v0,
                                                                 rowPl, rowPa);
    rowfinal_kernel  <<<dim3(RB),        dim3(256), 0, stream>>>(rowPl, rowPa, den, x0b);
    colpass_kernel   <<<dim3(36, 16, G), dim3(256), 0, stream>>>(Q1, Q2, K1, K2, idxb, v1,
                                                                 den, colP);
    colfinal_kernel  <<<dim3(RB),        dim3(256), 0, stream>>>(colP, x1b);
    outer_kernel     <<<dim3(72, 72, 2), dim3(256), 0, stream>>>(x0b, x1b, out);
}